// Round 5
// baseline (223.700 us; speedup 1.0000x reference)
//
#include <hip/hip_runtime.h>
#include <hip/hip_bf16.h>
#include <cstdint>

#define NN 8192
#define F 512
#define LOG2E 1.4426950408889634f

typedef __attribute__((ext_vector_type(8))) short bf16x8;
typedef __attribute__((ext_vector_type(4))) float f32x4;
typedef unsigned int uint32;
typedef unsigned long long u64;
typedef unsigned char uchar;

#define AS1 __attribute__((address_space(1)))
#define AS3 __attribute__((address_space(3)))
__device__ __forceinline__ void gload16(const void* g, void* l){
  __builtin_amdgcn_global_load_lds((const AS1 uint32*)g, (AS3 uint32*)l, 16, 0, 0);
}

__device__ __forceinline__ short f2bf(float x){
  __hip_bfloat16 h = __float2bfloat16(x);
  return *reinterpret_cast<short*>(&h);
}

// ---------- wa = W @ a1 / W @ a2 ----------
__global__ __launch_bounds__(256) void k_wa(const float* __restrict__ W, const float* __restrict__ attn,
                     float* __restrict__ wa){
  const int lane = threadIdx.x&63, wid = threadIdx.x>>6;
  const int id = blockIdx.x*4 + wid;
  const int b = id>>9, c = id&511;
  const float4* Wr = (const float4*)(W + (size_t)c*F);
  const float4* av = (const float4*)(attn + b*F);
  float s = 0.f;
  #pragma unroll
  for (int h=0;h<2;++h){
    const int k = lane + h*64;
    const float4 wv = Wr[k], a = av[k];
    s += wv.x*a.x + wv.y*a.y + wv.z*a.z + wv.w*a.w;
  }
  for (int off=32;off;off>>=1) s += __shfl_down(s,off);
  if (lane==0) wa[id] = s;
}

// ---------- W^T -> bf16 via LDS tile ----------
__global__ __launch_bounds__(256) void k_tw(const float* __restrict__ W, short* __restrict__ WbT){
  __shared__ short t[64][72];
  const int k0 = blockIdx.x*64, n0 = blockIdx.y*64;
  #pragma unroll
  for (int it=0;it<16;++it){
    const int idx = it*256 + threadIdx.x;
    const int r = idx>>6, c = idx&63;
    t[r][c] = f2bf(W[(size_t)(k0+r)*F + n0 + c]);
  }
  __syncthreads();
  #pragma unroll
  for (int it=0;it<2;++it){
    const int idx = it*256 + threadIdx.x;
    const int n = idx>>3, g = idx&7;
    short v[8];
    #pragma unroll
    for (int e=0;e<8;++e) v[e] = t[g*8+e][n];
    *(uint4*)(WbT + (size_t)(n0+n)*F + k0 + g*8) = *(const uint4*)v;
  }
}

// ---------- fused: s1L + packed bf16 u/w table + X->bf16 ----------
__global__ __launch_bounds__(256) void k_prep(const float* __restrict__ X, const float* __restrict__ wa,
    short* __restrict__ Xb, float* __restrict__ s1L, uint32* __restrict__ uwb){
  const int lane = threadIdx.x&63, wid = threadIdx.x>>6;
  const int row = blockIdx.x*4 + wid;
  const float4* X4 = (const float4*)(X + (size_t)row*F);
  const float4* A4 = (const float4*)wa;
  const float4* B4 = (const float4*)(wa + F);
  uint2* Xb4 = (uint2*)(Xb + (size_t)row*F);
  float a1 = 0.f, a2 = 0.f;
  #pragma unroll
  for (int h=0;h<2;++h){
    const int c = lane + h*64;
    const float4 x = X4[c];
    const float4 a = A4[c];
    const float4 b = B4[c];
    a1 += x.x*a.x + x.y*a.y + x.z*a.z + x.w*a.w;
    a2 += x.x*b.x + x.y*b.y + x.z*b.z + x.w*b.w;
    short o[4] = {f2bf(x.x),f2bf(x.y),f2bf(x.z),f2bf(x.w)};
    Xb4[c] = *(const uint2*)o;
  }
  for (int off=32;off;off>>=1){ a1 += __shfl_down(a1,off); a2 += __shfl_down(a2,off); }
  if (lane==0){
    const float s1 = a1*LOG2E, s2 = a2*LOG2E;
    s1L[row] = s1;
    const float u = exp2f(s2), w = exp2f(0.2f*s2);
    uwb[row] = (uint32)(unsigned short)f2bf(u) | ((uint32)(unsigned short)f2bf(w)<<16);
  }
}

// ---------- GEMM1: h = Xb @ WbT^T, writes HT[feature][node] bf16 ----------
__global__ __launch_bounds__(256,2) void k_gemm1(const short* __restrict__ Xb,
    const short* __restrict__ WbT, short* __restrict__ HT){
  __shared__ char smem[33280];
  short* At = (short*)smem;
  short* Bt = (short*)(smem + 16384);
  const int tid=threadIdx.x, lane=tid&63, wid=tid>>6;
  const int m0 = blockIdx.x*128, n0 = blockIdx.y*128;
  f32x4 acc[2][8];
  #pragma unroll
  for (int a=0;a<2;++a)
    #pragma unroll
    for (int b=0;b<8;++b) acc[a][b] = (f32x4){0.f,0.f,0.f,0.f};

  for (int t=0;t<8;++t){
    const int k0 = t*64;
    __syncthreads();
    #pragma unroll
    for (int rnd=0;rnd<4;++rnd){
      const int s = rnd*256 + tid;
      const int n = s>>3, kc = s&7;
      uint4 va = *(const uint4*)(Xb  + (size_t)(m0+n)*F + k0 + kc*8);
      uint4 vb = *(const uint4*)(WbT + (size_t)(n0+n)*F + k0 + kc*8);
      const int off = n*128 + ((kc^(n&7))*16);
      *(uint4*)((char*)At + off) = va;
      *(uint4*)((char*)Bt + off) = vb;
    }
    __syncthreads();
    #pragma unroll
    for (int ks=0;ks<2;++ks){
      const int kc = ks*4 + (lane>>4);
      int r0 = wid*32 + (lane&15);
      int r1 = r0 + 16;
      bf16x8 af0 = *(const bf16x8*)((char*)At + r0*128 + ((kc^(r0&7))*16));
      bf16x8 af1 = *(const bf16x8*)((char*)At + r1*128 + ((kc^(r1&7))*16));
      #pragma unroll
      for (int nf=0;nf<8;++nf){
        const int c = nf*16 + (lane&15);
        bf16x8 bf = *(const bf16x8*)((char*)Bt + c*128 + ((kc^(c&7))*16));
        acc[0][nf] = __builtin_amdgcn_mfma_f32_16x16x32_bf16(af0, bf, acc[0][nf],0,0,0);
        acc[1][nf] = __builtin_amdgcn_mfma_f32_16x16x32_bf16(af1, bf, acc[1][nf],0,0,0);
      }
    }
  }
  __syncthreads();
  short* ct = (short*)smem;                 // [128][130] bf16
  #pragma unroll
  for (int mf=0;mf<2;++mf)
    #pragma unroll
    for (int nf=0;nf<8;++nf)
      #pragma unroll
      for (int q=0;q<4;++q){
        int r = wid*32 + mf*16 + (lane>>4)*4 + q;
        int c = nf*16 + (lane&15);
        ct[r*130+c] = f2bf(acc[mf][nf][q]);
      }
  __syncthreads();
  {
    const int c = tid>>1, ih0 = (tid&1)*64;
    #pragma unroll
    for (int i8=0;i8<8;++i8){
      short v[8];
      #pragma unroll
      for (int e=0;e<8;++e) v[e] = ct[(ih0+i8*8+e)*130 + c];
      *(uint4*)(HT + (size_t)(n0+c)*NN + m0 + ih0 + i8*8) = *(const uint4*)v;
    }
  }
}

// ---------- stats: stream adj once, WRITE bf16 unnormalized weights Pt + invZ ----------
// 4 rows per block; uwb staged in LDS once per block.
__global__ __launch_bounds__(256) void k_stats(const int* __restrict__ adj,
    const float* __restrict__ s1L, const uint32* __restrict__ uwb,
    short* __restrict__ Pt, float* __restrict__ invZ){
  __shared__ uint32 uwl[NN];          // 32KB packed bf16 (u,w)
  __shared__ float zred[4][4];
  const int tid=threadIdx.x, lane=tid&63, wid=tid>>6;
  const int r0 = blockIdx.x*4;
  for (int i=tid;i<NN/4;i+=256) ((uint4*)uwl)[i] = ((const uint4*)uwb)[i];
  float A0[4], B0[4];
  #pragma unroll
  for (int rr=0;rr<4;++rr){
    const float s1 = s1L[r0+rr];
    A0[rr] = exp2f(s1);
    B0[rr] = exp2f(0.2f*s1);
  }
  __syncthreads();
  float z[4] = {0.f,0.f,0.f,0.f};
  #pragma unroll
  for (int it=0;it<8;++it){
    const int c4 = it*256 + tid;          // cols 4*c4 .. +3
    const uint4 uq = *(const uint4*)&uwl[c4*4];
    const uint32 qa[4] = {uq.x,uq.y,uq.z,uq.w};
    float u[4], w[4];
    #pragma unroll
    for (int e=0;e<4;++e){
      u[e] = __uint_as_float(qa[e]<<16);
      w[e] = __uint_as_float(qa[e]&0xffff0000u);
    }
    #pragma unroll
    for (int rr=0;rr<4;++rr){
      const int4 a = *(const int4*)(adj + (size_t)(r0+rr)*NN + c4*4);
      const int aa[4] = {a.x,a.y,a.z,a.w};
      short av[4];
      #pragma unroll
      for (int e=0;e<4;++e){
        const float t = fmaxf(A0[rr]*u[e], B0[rr]*w[e]);
        const float v = (aa[e] > 0) ? t : 0.f;
        z[rr] += v;
        av[e] = f2bf(v);
      }
      *(uint2*)(Pt + (size_t)(r0+rr)*NN + c4*4) = *(const uint2*)av;
    }
  }
  for (int off=32;off;off>>=1){
    #pragma unroll
    for (int rr=0;rr<4;++rr) z[rr] += __shfl_down(z[rr],off);
  }
  if (lane==0){
    #pragma unroll
    for (int rr=0;rr<4;++rr) zred[wid][rr] = z[rr];
  }
  __syncthreads();
  if (tid < 4){
    const float Z = zred[0][tid]+zred[1][tid]+zred[2][tid]+zred[3][tid];
    invZ[r0+tid] = 1.f/Z;
  }
}

// ---------- PV: plain bf16 GEMM, partial = Pt[m,:]k-slice @ HT^T. ----------
// BM=128,BN=128,BK=64, 4 waves of 64x64, split-K=4, both tiles via global_load_lds.
__global__ __launch_bounds__(256,4) void k_pv(const short* __restrict__ Pt,
    const short* __restrict__ HT,
    float* __restrict__ P0, float* __restrict__ P1,
    float* __restrict__ P2, float* __restrict__ P3, int ksteps){
  __shared__ short At[128*64];    // 16KB swizzled
  __shared__ short Btm[128*64];   // 16KB swizzled
  const int tid=threadIdx.x, lane=tid&63, wid=tid>>6;
  const int m0 = blockIdx.x*128, n0 = blockIdx.y*128;
  const int kz0 = blockIdx.z * (ksteps*64);
  float* const outs[4] = {P0,P1,P2,P3};
  float* outP = outs[blockIdx.z];

  // staging: round r slot s=r*256+wid*64+lane -> row n=s>>3 (linear), holds kc=(lane&7)^(n&7)
  const int bn  = wid*8 + (lane>>3);
  const int bkc = (lane&7) ^ ((lane>>3)&7);
  const short* gA = Pt + (size_t)(m0+bn)*NN + kz0 + bkc*8;   // + r*32*NN + k0
  const short* gB = HT + (size_t)(n0+bn)*NN + kz0 + bkc*8;
  char* ldsA = (char*)At  + wid*1024;                         // + r*4096
  char* ldsB = (char*)Btm + wid*1024;

  f32x4 acc[4][4];
  #pragma unroll
  for (int i=0;i<4;++i)
    #pragma unroll
    for (int j=0;j<4;++j) acc[i][j] = (f32x4){0.f,0.f,0.f,0.f};

  const int wr = wid>>1, wc = wid&1;

  for (int t=0;t<ksteps;++t){
    const int k0 = t*64;
    #pragma unroll
    for (int r=0;r<4;++r) gload16(gA + r*(32*NN) + k0, ldsA + r*4096);
    #pragma unroll
    for (int r=0;r<4;++r) gload16(gB + r*(32*NN) + k0, ldsB + r*4096);
    __syncthreads();   // drains vmcnt: tiles ready
    #pragma unroll
    for (int ks=0;ks<2;++ks){
      const int kc = ks*4 + (lane>>4);
      bf16x8 af[4];
      #pragma unroll
      for (int mf=0;mf<4;++mf){
        const int r = wr*64 + mf*16 + (lane&15);
        af[mf] = *(const bf16x8*)((char*)At + r*128 + ((kc^(r&7))*16));
      }
      #pragma unroll
      for (int nf=0;nf<4;++nf){
        const int c = wc*64 + nf*16 + (lane&15);
        const bf16x8 bv = *(const bf16x8*)((char*)Btm + c*128 + ((kc^(c&7))*16));
        #pragma unroll
        for (int mf=0;mf<4;++mf)
          acc[mf][nf] = __builtin_amdgcn_mfma_f32_16x16x32_bf16(af[mf], bv, acc[mf][nf],0,0,0);
      }
    }
    __syncthreads();   // LDS reads done before next overwrite
  }
  #pragma unroll
  for (int mf=0;mf<4;++mf)
    #pragma unroll
    for (int nf=0;nf<4;++nf){
      const int col = n0 + wc*64 + nf*16 + (lane&15);
      #pragma unroll
      for (int q=0;q<4;++q){
        const int r = m0 + wr*64 + mf*16 + (lane>>4)*4 + q;
        outP[(size_t)r*F + col] = acc[mf][nf][q];
      }
    }
}

// ---------- reduce: out = elu( (P0+P1+P2+P3) * invZ[row] ) ----------
__global__ __launch_bounds__(256) void k_red(const float* __restrict__ P1,
    const float* __restrict__ P2, const float* __restrict__ P3,
    const float* __restrict__ invZ, float* __restrict__ out, int ks){
  const size_t i = ((size_t)blockIdx.x*256 + threadIdx.x)*4;
  float4 a = *(float4*)(out+i);
  if (ks > 1){
    const float4 b1 = *(const float4*)(P1+i);
    const float4 b2 = *(const float4*)(P2+i);
    const float4 b3 = *(const float4*)(P3+i);
    a.x += b1.x+b2.x+b3.x; a.y += b1.y+b2.y+b3.y;
    a.z += b1.z+b2.z+b3.z; a.w += b1.w+b2.w+b3.w;
  }
  const float s = invZ[i>>9];
  a.x*=s; a.y*=s; a.z*=s; a.w*=s;
  a.x = (a.x>0.f)?a.x:expm1f(a.x);
  a.y = (a.y>0.f)?a.y:expm1f(a.y);
  a.z = (a.z>0.f)?a.z:expm1f(a.z);
  a.w = (a.w>0.f)?a.w:expm1f(a.w);
  *(float4*)(out+i) = a;
}

extern "C" void kernel_launch(void* const* d_in, const int* in_sizes, int n_in,
                              void* d_out, int out_size, void* d_ws, size_t ws_size,
                              hipStream_t stream) {
  (void)in_sizes; (void)n_in; (void)out_size;
  const int*   adj  = (const int*)d_in[0];
  const float* X    = (const float*)d_in[1];
  const float* W    = (const float*)d_in[2];
  const float* attn = (const float*)d_in[3];
  float* out = (float*)d_out;
  char* ws = (char*)d_ws;
  // ws observed ~1 GiB (harness poison fill = 1.07e9 B). Layout:
  short*  Pt   = (short*)(ws);                        // 134.2 MB bf16 unnorm weights
  short*  HT   = (short*)(ws + 134217728);            // 8 MB
  short*  Xb   = (short*)(ws + 142606336);            // 8 MB
  short*  WbT  = (short*)(ws + 150994944);            // 0.5 MB
  float*  s1L  = (float*)(ws + 151519232);            // 32 KB
  uint32* uwb  = (uint32*)(ws + 151552000);           // 32 KB
  float*  invZ = (float*)(ws + 151584768);            // 32 KB
  float*  wa   = (float*)(ws + 151617536);            // 4 KB
  float*  P1   = (float*)(ws + 151621632);            // 16.78 MB
  float*  P2   = (float*)(ws + 168398848);            // 16.78 MB
  float*  P3   = (float*)(ws + 185176064);            // 16.78 MB  (end ~202 MB)
  const int KS = (ws_size >= 201953280ull) ? 4 : 1;
  const int ksteps = 128/KS;

  k_wa   <<<dim3(256),   dim3(256), 0, stream>>>(W, attn, wa);
  k_tw   <<<dim3(8,8),   dim3(256), 0, stream>>>(W, WbT);
  k_prep <<<dim3(2048),  dim3(256), 0, stream>>>(X, wa, Xb, s1L, uwb);
  k_gemm1<<<dim3(64,4),  dim3(256), 0, stream>>>(Xb, WbT, HT);
  k_stats<<<dim3(2048),  dim3(256), 0, stream>>>(adj, s1L, uwb, Pt, invZ);
  k_pv   <<<dim3(64,4,KS), dim3(256), 0, stream>>>(Pt, HT, out, P1, P2, P3, ksteps);
  k_red  <<<dim3(4096),  dim3(256), 0, stream>>>(P1, P2, P3, invZ, out, KS);
}

// Round 6
// 197.116 us; speedup vs baseline: 1.1349x; 1.1349x over previous
//
#include <hip/hip_runtime.h>
#include <hip/hip_bf16.h>
#include <cstdint>

#define NN 8192
#define F 512
#define LOG2E 1.4426950408889634f

typedef __attribute__((ext_vector_type(8))) short bf16x8;
typedef __attribute__((ext_vector_type(4))) float f32x4;
typedef unsigned int uint32;
typedef unsigned long long u64;
typedef unsigned char uchar;

#define AS1 __attribute__((address_space(1)))
#define AS3 __attribute__((address_space(3)))
__device__ __forceinline__ void gload16(const void* g, void* l){
  __builtin_amdgcn_global_load_lds((const AS1 uint32*)g, (AS3 uint32*)l, 16, 0, 0);
}

__device__ __forceinline__ short f2bf(float x){
  __hip_bfloat16 h = __float2bfloat16(x);
  return *reinterpret_cast<short*>(&h);
}

// ---------- wa = W @ a1 / W @ a2 ----------
__global__ __launch_bounds__(256) void k_wa(const float* __restrict__ W, const float* __restrict__ attn,
                     float* __restrict__ wa){
  const int lane = threadIdx.x&63, wid = threadIdx.x>>6;
  const int id = blockIdx.x*4 + wid;
  const int b = id>>9, c = id&511;
  const float4* Wr = (const float4*)(W + (size_t)c*F);
  const float4* av = (const float4*)(attn + b*F);
  float s = 0.f;
  #pragma unroll
  for (int h=0;h<2;++h){
    const int k = lane + h*64;
    const float4 wv = Wr[k], a = av[k];
    s += wv.x*a.x + wv.y*a.y + wv.z*a.z + wv.w*a.w;
  }
  for (int off=32;off;off>>=1) s += __shfl_down(s,off);
  if (lane==0) wa[id] = s;
}

// ---------- W^T -> bf16 via LDS tile ----------
__global__ __launch_bounds__(256) void k_tw(const float* __restrict__ W, short* __restrict__ WbT){
  __shared__ short t[64][72];
  const int k0 = blockIdx.x*64, n0 = blockIdx.y*64;
  #pragma unroll
  for (int it=0;it<16;++it){
    const int idx = it*256 + threadIdx.x;
    const int r = idx>>6, c = idx&63;
    t[r][c] = f2bf(W[(size_t)(k0+r)*F + n0 + c]);
  }
  __syncthreads();
  #pragma unroll
  for (int it=0;it<2;++it){
    const int idx = it*256 + threadIdx.x;
    const int n = idx>>3, g = idx&7;
    short v[8];
    #pragma unroll
    for (int e=0;e<8;++e) v[e] = t[g*8+e][n];
    *(uint4*)(WbT + (size_t)(n0+n)*F + k0 + g*8) = *(const uint4*)v;
  }
}

// ---------- fused: X->bf16 + per-row (A0,B0) + per-col (u,w) tables ----------
__global__ __launch_bounds__(256) void k_prep(const float* __restrict__ X, const float* __restrict__ wa,
    short* __restrict__ Xb, float2* __restrict__ uwf, float2* __restrict__ rowAB){
  const int lane = threadIdx.x&63, wid = threadIdx.x>>6;
  const int row = blockIdx.x*4 + wid;
  const float4* X4 = (const float4*)(X + (size_t)row*F);
  const float4* A4 = (const float4*)wa;
  const float4* B4 = (const float4*)(wa + F);
  uint2* Xb4 = (uint2*)(Xb + (size_t)row*F);
  float a1 = 0.f, a2 = 0.f;
  #pragma unroll
  for (int h=0;h<2;++h){
    const int c = lane + h*64;
    const float4 x = X4[c];
    const float4 a = A4[c];
    const float4 b = B4[c];
    a1 += x.x*a.x + x.y*a.y + x.z*a.z + x.w*a.w;
    a2 += x.x*b.x + x.y*b.y + x.z*b.z + x.w*b.w;
    short o[4] = {f2bf(x.x),f2bf(x.y),f2bf(x.z),f2bf(x.w)};
    Xb4[c] = *(const uint2*)o;
  }
  for (int off=32;off;off>>=1){ a1 += __shfl_down(a1,off); a2 += __shfl_down(a2,off); }
  if (lane==0){
    const float s1 = a1*LOG2E, s2 = a2*LOG2E;
    rowAB[row] = make_float2(exp2f(s1), exp2f(0.2f*s1));
    uwf[row]   = make_float2(exp2f(s2), exp2f(0.2f*s2));
  }
}

// ---------- GEMM1: h = Xb @ WbT^T, writes HT[feature][node] bf16 ----------
__global__ __launch_bounds__(256,2) void k_gemm1(const short* __restrict__ Xb,
    const short* __restrict__ WbT, short* __restrict__ HT){
  __shared__ char smem[33280];
  short* At = (short*)smem;
  short* Bt = (short*)(smem + 16384);
  const int tid=threadIdx.x, lane=tid&63, wid=tid>>6;
  const int m0 = blockIdx.x*128, n0 = blockIdx.y*128;
  f32x4 acc[2][8];
  #pragma unroll
  for (int a=0;a<2;++a)
    #pragma unroll
    for (int b=0;b<8;++b) acc[a][b] = (f32x4){0.f,0.f,0.f,0.f};

  for (int t=0;t<8;++t){
    const int k0 = t*64;
    __syncthreads();
    #pragma unroll
    for (int rnd=0;rnd<4;++rnd){
      const int s = rnd*256 + tid;
      const int n = s>>3, kc = s&7;
      uint4 va = *(const uint4*)(Xb  + (size_t)(m0+n)*F + k0 + kc*8);
      uint4 vb = *(const uint4*)(WbT + (size_t)(n0+n)*F + k0 + kc*8);
      const int off = n*128 + ((kc^(n&7))*16);
      *(uint4*)((char*)At + off) = va;
      *(uint4*)((char*)Bt + off) = vb;
    }
    __syncthreads();
    #pragma unroll
    for (int ks=0;ks<2;++ks){
      const int kc = ks*4 + (lane>>4);
      int r0 = wid*32 + (lane&15);
      int r1 = r0 + 16;
      bf16x8 af0 = *(const bf16x8*)((char*)At + r0*128 + ((kc^(r0&7))*16));
      bf16x8 af1 = *(const bf16x8*)((char*)At + r1*128 + ((kc^(r1&7))*16));
      #pragma unroll
      for (int nf=0;nf<8;++nf){
        const int c = nf*16 + (lane&15);
        bf16x8 bf = *(const bf16x8*)((char*)Bt + c*128 + ((kc^(c&7))*16));
        acc[0][nf] = __builtin_amdgcn_mfma_f32_16x16x32_bf16(af0, bf, acc[0][nf],0,0,0);
        acc[1][nf] = __builtin_amdgcn_mfma_f32_16x16x32_bf16(af1, bf, acc[1][nf],0,0,0);
      }
    }
  }
  __syncthreads();
  short* ct = (short*)smem;                 // [128][130] bf16
  #pragma unroll
  for (int mf=0;mf<2;++mf)
    #pragma unroll
    for (int nf=0;nf<8;++nf)
      #pragma unroll
      for (int q=0;q<4;++q){
        int r = wid*32 + mf*16 + (lane>>4)*4 + q;
        int c = nf*16 + (lane&15);
        ct[r*130+c] = f2bf(acc[mf][nf][q]);
      }
  __syncthreads();
  {
    const int c = tid>>1, ih0 = (tid&1)*64;
    #pragma unroll
    for (int i8=0;i8<8;++i8){
      short v[8];
      #pragma unroll
      for (int e=0;e<8;++e) v[e] = ct[(ih0+i8*8+e)*130 + c];
      *(uint4*)(HT + (size_t)(n0+c)*NN + m0 + ih0 + i8*8) = *(const uint4*)v;
    }
  }
}

// ---------- PV fused: stream adjacency, gen weights, MFMA. ----------
// BM=64, BN=512(full), BK=64, 4 waves of 64x128, split-K=4.
__global__ __launch_bounds__(256,2) void k_pv(const int* __restrict__ adj,
    const short* __restrict__ HT, const float2* __restrict__ uwf,
    const float2* __restrict__ rowAB, float* __restrict__ Zp,
    float* __restrict__ P0, float* __restrict__ P1,
    float* __restrict__ P2, float* __restrict__ P3, int ksteps){
  __shared__ short Bt[512*64];    // 64KB, swizzled [feature][kchunk]
  __shared__ short At[64*64];     // 8KB, swizzled weights
  const int tid=threadIdx.x, lane=tid&63, wid=tid>>6;
  const int m0 = blockIdx.x*64;
  const int kz = blockIdx.y;
  const int kz0 = kz*(ksteps*64);
  float* const outs[4] = {P0,P1,P2,P3};
  float* outP = outs[kz];

  // ---- B staging geometry: iter i stages slot s=i*256+tid -> f=i*32+(tid>>3), chunk c=tid&7
  // holds kc = c ^ (f&7) (pre-swizzled source, linear dest)
  const int bkc = (tid&7) ^ ((tid>>3)&7);
  const short* gB = HT + (size_t)(tid>>3)*NN + kz0 + bkc*8;  // + i*32*NN + k0r
  char* ldsB = (char*)Bt + tid*16;                            // + i*4096

  // ---- A-gen geometry: thread -> row r=tid>>2, col group q=tid&3 (16 cols)
  const int r = tid>>2, q = tid&3;
  const float2 E = rowAB[m0 + r];
  const float A0 = E.x, B0 = E.y;
  const int* adjp = adj + (size_t)(m0+r)*NN + kz0 + q*16;
  const float2* uwp = uwf + kz0 + q*16;
  const int ad0 = r*128 + (((2*q  )^(r&7))*16);
  const int ad1 = r*128 + (((2*q+1)^(r&7))*16);

  f32x4 acc[4][8];
  #pragma unroll
  for (int i=0;i<4;++i)
    #pragma unroll
    for (int j=0;j<8;++j) acc[i][j] = (f32x4){0.f,0.f,0.f,0.f};
  float zacc = 0.f;

  // prefetch regs for t=0
  int4 a0,a1,a2,a3;
  float4 uw[8];
  a0 = *(const int4*)(adjp+0); a1 = *(const int4*)(adjp+4);
  a2 = *(const int4*)(adjp+8); a3 = *(const int4*)(adjp+12);
  #pragma unroll
  for (int j=0;j<8;++j) uw[j] = ((const float4*)uwp)[j];

  for (int t=0;t<ksteps;++t){
    const int k0r = t*64;
    // stage B tile (512x64) via global_load_lds
    #pragma unroll
    for (int i=0;i<16;++i) gload16(gB + (size_t)i*32*NN + k0r, ldsB + i*4096);
    // A-gen from prefetched regs
    {
      const int aa[16] = {a0.x,a0.y,a0.z,a0.w, a1.x,a1.y,a1.z,a1.w,
                          a2.x,a2.y,a2.z,a2.w, a3.x,a3.y,a3.z,a3.w};
      short av0[8], av1[8];
      #pragma unroll
      for (int e=0;e<16;++e){
        const float u = (e&1) ? uw[e>>1].z : uw[e>>1].x;
        const float w = (e&1) ? uw[e>>1].w : uw[e>>1].y;
        float v = fmaxf(A0*u, B0*w);
        v = (aa[e] > 0) ? v : 0.f;
        zacc += v;
        if (e<8) av0[e] = f2bf(v); else av1[e-8] = f2bf(v);
      }
      *(uint4*)((char*)At + ad0) = *(const uint4*)av0;
      *(uint4*)((char*)At + ad1) = *(const uint4*)av1;
    }
    __syncthreads();      // B tile + A tile ready
    // prefetch next-step regs (in flight during MFMA phase)
    if (t+1 < ksteps){
      const int kn = (t+1)*64;
      a0 = *(const int4*)(adjp+kn+0);  a1 = *(const int4*)(adjp+kn+4);
      a2 = *(const int4*)(adjp+kn+8);  a3 = *(const int4*)(adjp+kn+12);
      #pragma unroll
      for (int j=0;j<8;++j) uw[j] = ((const float4*)(uwp+kn))[j];
    }
    // MFMA: wave wid covers features wid*128 .. +127
    #pragma unroll
    for (int ks=0;ks<2;++ks){
      const int kc = ks*4 + (lane>>4);
      bf16x8 af[4];
      #pragma unroll
      for (int mf=0;mf<4;++mf){
        const int rr = mf*16 + (lane&15);
        af[mf] = *(const bf16x8*)((char*)At + rr*128 + ((kc^(rr&7))*16));
      }
      #pragma unroll
      for (int nf=0;nf<8;++nf){
        const int c = wid*128 + nf*16 + (lane&15);
        const bf16x8 bv = *(const bf16x8*)((char*)Bt + c*128 + ((kc^(c&7))*16));
        #pragma unroll
        for (int mf=0;mf<4;++mf)
          acc[mf][nf] = __builtin_amdgcn_mfma_f32_16x16x32_bf16(af[mf], bv, acc[mf][nf],0,0,0);
      }
    }
    __syncthreads();      // tile reads done before next overwrite
  }
  // per-slice Z: 4 threads per row -> combine
  zacc += __shfl_xor(zacc, 1);
  zacc += __shfl_xor(zacc, 2);
  if (q == 0) Zp[(size_t)kz*NN + m0 + r] = zacc;
  // raw f32 partial store
  #pragma unroll
  for (int mf=0;mf<4;++mf)
    #pragma unroll
    for (int nf=0;nf<8;++nf){
      const int col = wid*128 + nf*16 + (lane&15);
      #pragma unroll
      for (int qq=0;qq<4;++qq){
        const int row = m0 + mf*16 + (lane>>4)*4 + qq;
        outP[(size_t)row*F + col] = acc[mf][nf][qq];
      }
    }
}

// ---------- reduce: out = elu( (P0+P1+P2+P3) / Z ) ----------
__global__ __launch_bounds__(256) void k_red(const float* __restrict__ P1,
    const float* __restrict__ P2, const float* __restrict__ P3,
    const float* __restrict__ Zp, float* __restrict__ out, int ks){
  const size_t i = ((size_t)blockIdx.x*256 + threadIdx.x)*4;
  const int row = (int)(i >> 9);
  float4 a = *(float4*)(out+i);
  float Z = Zp[row];
  if (ks > 1){
    Z += Zp[NN+row] + Zp[2*NN+row] + Zp[3*NN+row];
    const float4 b1 = *(const float4*)(P1+i);
    const float4 b2 = *(const float4*)(P2+i);
    const float4 b3 = *(const float4*)(P3+i);
    a.x += b1.x+b2.x+b3.x; a.y += b1.y+b2.y+b3.y;
    a.z += b1.z+b2.z+b3.z; a.w += b1.w+b2.w+b3.w;
  }
  const float s = 1.f/Z;
  a.x*=s; a.y*=s; a.z*=s; a.w*=s;
  a.x = (a.x>0.f)?a.x:expm1f(a.x);
  a.y = (a.y>0.f)?a.y:expm1f(a.y);
  a.z = (a.z>0.f)?a.z:expm1f(a.z);
  a.w = (a.w>0.f)?a.w:expm1f(a.w);
  *(float4*)(out+i) = a;
}

extern "C" void kernel_launch(void* const* d_in, const int* in_sizes, int n_in,
                              void* d_out, int out_size, void* d_ws, size_t ws_size,
                              hipStream_t stream) {
  (void)in_sizes; (void)n_in; (void)out_size;
  const int*   adj  = (const int*)d_in[0];
  const float* X    = (const float*)d_in[1];
  const float* W    = (const float*)d_in[2];
  const float* attn = (const float*)d_in[3];
  float* out = (float*)d_out;
  char* ws = (char*)d_ws;
  short*  HT   = (short*)(ws);                 // 8 MB
  short*  Xb   = (short*)(ws + 8388608);       // 8 MB
  short*  WbT  = (short*)(ws + 16777216);      // 0.5 MB
  float2* uwf  = (float2*)(ws + 17301504);     // 64 KB
  float2* rowAB= (float2*)(ws + 17367040);     // 64 KB
  float*  wa   = (float*)(ws + 17432576);      // 4 KB
  float*  Zp   = (float*)(ws + 17436672);      // 128 KB (4 x 8192)
  float*  P1   = (float*)(ws + 17567744);      // 16.78 MB
  float*  P2   = (float*)(ws + 34344960);      // 16.78 MB
  float*  P3   = (float*)(ws + 51122176);      // 16.78 MB (end ~68 MB)
  const int KS = (ws_size >= 67899392ull) ? 4 : 1;
  const int ksteps = 128/KS;

  k_wa   <<<dim3(256),    dim3(256), 0, stream>>>(W, attn, wa);
  k_tw   <<<dim3(8,8),    dim3(256), 0, stream>>>(W, WbT);
  k_prep <<<dim3(2048),   dim3(256), 0, stream>>>(X, wa, Xb, uwf, rowAB);
  k_gemm1<<<dim3(64,4),   dim3(256), 0, stream>>>(Xb, WbT, HT);
  k_pv   <<<dim3(128,KS), dim3(256), 0, stream>>>(adj, HT, uwf, rowAB, Zp, out, P1, P2, P3, ksteps);
  k_red  <<<dim3(4096),   dim3(256), 0, stream>>>(P1, P2, P3, Zp, out, KS);
}